// Round 4
// baseline (1793.714 us; speedup 1.0000x reference)
//
#include <hip/hip_runtime.h>
#include <hip/hip_bf16.h>

typedef _Float16 half8  __attribute__((ext_vector_type(8)));
typedef _Float16 half4_t __attribute__((ext_vector_type(4)));
typedef float    floatx4 __attribute__((ext_vector_type(4)));
typedef int      intx4   __attribute__((ext_vector_type(4)));

#define B_DIM   16384
#define IN_D    2048
#define HV_D    8192
#define NC      1000
#define NCP     1024
#define SCORES_N (B_DIM * NC)

// async global->LDS, 16B per lane; LDS side is wave-uniform base + lane*16
#define GLD16(gp, lp) __builtin_amdgcn_global_load_lds( \
    (const __attribute__((address_space(1))) void*)(gp), \
    (__attribute__((address_space(3))) void*)(lp), 16, 0, 0)

// ---------- P1: Dekker split x (fp32) -> x_hi + x_lo (fp16), exact vs fp32 ----------
__global__ void k_split(const float* __restrict__ x, _Float16* __restrict__ xh,
                        _Float16* __restrict__ xl) {
    size_t i = (size_t)blockIdx.x * 256 + threadIdx.x;
    floatx4 v = ((const floatx4*)x)[i];
    half4_t h, l;
#pragma unroll
    for (int j = 0; j < 4; ++j) {
        _Float16 hh = (_Float16)v[j];
        h[j] = hh;
        l[j] = (_Float16)(v[j] - (float)hh);
    }
    ((half4_t*)xh)[i] = h;
    ((half4_t*)xl)[i] = l;
}

// ---------- P2: proj [K=2048][N=8192] fp32 -> projT [N][K] fp16 (LDS-tiled) ----------
__global__ void k_transpose_proj(const float* __restrict__ p, _Float16* __restrict__ pT) {
    __shared__ float tile[64][65];
    const int t = threadIdx.x;
    const int nt = blockIdx.x * 64;
    const int kt = blockIdx.y * 64;
    const int tr = t >> 4, tc = (t & 15) * 4;
#pragma unroll
    for (int s = 0; s < 4; ++s) {
        int r = tr + s * 16;
        floatx4 v = *(const floatx4*)&p[(size_t)(kt + r) * HV_D + nt + tc];
        tile[r][tc] = v[0]; tile[r][tc + 1] = v[1];
        tile[r][tc + 2] = v[2]; tile[r][tc + 3] = v[3];
    }
    __syncthreads();
#pragma unroll
    for (int s = 0; s < 4; ++s) {
        int rn = tr + s * 16;
        half4_t o;
#pragma unroll
        for (int j = 0; j < 4; ++j) o[j] = (_Float16)tile[tc + j][rn];
        *(half4_t*)&pT[(size_t)(nt + rn) * IN_D + kt + tc] = o;
    }
}

// ---------- P3: class_hv [8192][1000] fp32 -> classT [1024][8192] i8 (coalesced, LDS transpose) ----------
__global__ void k_pack_class(const float* __restrict__ c, signed char* __restrict__ cT) {
    __shared__ signed char tile[64][68];
    const int t = threadIdx.x;
    const int nt = blockIdx.x * 64;   // 16 n-tiles
    const int kt = blockIdx.y * 64;   // 128 k-tiles
    const int nl = t & 63;
    const int n = nt + nl;
#pragma unroll
    for (int s = 0; s < 16; ++s) {
        const int kl = s * 4 + (t >> 6);
        signed char v = 0;
        if (n < NC) {
            float f = c[(size_t)(kt + kl) * NC + n];
            v = (f >= 0.f) ? (signed char)1 : (signed char)-1;
        }
        tile[kl][nl] = v;
    }
    __syncthreads();
    const int wn = t >> 2;
    const int wk = (t & 3) * 16;
    intx4 o;
    signed char* ob = (signed char*)&o;
#pragma unroll
    for (int j = 0; j < 16; ++j) ob[j] = tile[wk + j][wn];
    *(intx4*)&cT[(size_t)(nt + wn) * HV_D + kt + wk] = o;
}

// ---------- G1: hv = x@proj via fp16 hi/lo split, binarize, write fp32 + i8 ----------
// 128(M)x256(N) block, BK=32, DOUBLE-BUFFERED LDS (prefetch tile i+1 while computing tile i,
// so the vmcnt(0) drain at the barrier lands on ~1-iter-old loads instead of fresh ones).
// Rows are 64 B = 4 chunks; swizzle: chunk c of row r stored at c ^ ((r ^ r>>2)&3)
// -> per quarter-wave reads hit 8 distinct 4-bank groups x 2 lanes = conflict-free.
__launch_bounds__(256, 2)
__global__ void k_gemm1(const _Float16* __restrict__ xh, const _Float16* __restrict__ xl,
                        const _Float16* __restrict__ pT,
                        float* __restrict__ hv_out, signed char* __restrict__ hvb) {
    __shared__ _Float16 sAh[2][128 * 32];   // 8 KB per buf
    __shared__ _Float16 sAl[2][128 * 32];   // 8 KB per buf
    __shared__ _Float16 sB [2][256 * 32];   // 16 KB per buf
    const int t = threadIdx.x;
    const int w = t >> 6, l = t & 63;
    const int m0 = blockIdx.y * 128, n0 = blockIdx.x * 256;
    const int wm = (w >> 1) * 64, wn = (w & 1) * 128;
    const int lm = l & 15, kq = l >> 4;
    // staging: round covers 64 rows; row = i*64 + (t>>2), source chunk xor-swizzled
    const int sr  = t >> 2;
    const int sch = (t & 3) ^ ((sr ^ (sr >> 2)) & 3);
    // fragment read swizzle (f16 units): rows within a 16-row tile have (r^r>>2)&3 = (lm^lm>>2)&3
    const int csw = ((kq ^ ((lm ^ (lm >> 2)) & 3)) & 3) * 8;

    floatx4 acc[4][8] = {};

    auto stage = [&](int k0, int p) {
#pragma unroll
        for (int i = 0; i < 2; ++i) {
            const size_t ga = (size_t)(m0 + i * 64 + sr) * IN_D + k0 + sch * 8;
            GLD16(xh + ga, (char*)&sAh[p][i * 2048] + t * 16);
            GLD16(xl + ga, (char*)&sAl[p][i * 2048] + t * 16);
        }
#pragma unroll
        for (int i = 0; i < 4; ++i) {
            const size_t gb = (size_t)(n0 + i * 64 + sr) * IN_D + k0 + sch * 8;
            GLD16(pT + gb, (char*)&sB[p][i * 2048] + t * 16);
        }
    };

    stage(0, 0);
    const int NIT = IN_D / 32;   // 64
    for (int it = 0; it < NIT; ++it) {
        const int p = it & 1;
        __syncthreads();                         // drains stage(it); frees buf p^1
        if (it + 1 < NIT) stage((it + 1) * 32, p ^ 1);
        half8 b[8];
#pragma unroll
        for (int ns = 0; ns < 8; ++ns)
            b[ns] = *(const half8*)&sB[p][(wn + ns * 16 + lm) * 32 + csw];
#pragma unroll
        for (int ms = 0; ms < 4; ++ms) {
            half8 a = *(const half8*)&sAh[p][(wm + ms * 16 + lm) * 32 + csw];
#pragma unroll
            for (int ns = 0; ns < 8; ++ns)
                acc[ms][ns] = __builtin_amdgcn_mfma_f32_16x16x32_f16(a, b[ns], acc[ms][ns], 0, 0, 0);
        }
#pragma unroll
        for (int ms = 0; ms < 4; ++ms) {
            half8 a = *(const half8*)&sAl[p][(wm + ms * 16 + lm) * 32 + csw];
#pragma unroll
            for (int ns = 0; ns < 8; ++ns)
                acc[ms][ns] = __builtin_amdgcn_mfma_f32_16x16x32_f16(a, b[ns], acc[ms][ns], 0, 0, 0);
        }
    }

    // epilogue: C/D layout col=lane&15, row=(lane>>4)*4+reg
#pragma unroll
    for (int ms = 0; ms < 4; ++ms) {
#pragma unroll
        for (int ns = 0; ns < 8; ++ns) {
            const int m = m0 + wm + ms * 16 + kq * 4;
            const int n = n0 + wn + ns * 16 + lm;
#pragma unroll
            for (int r = 0; r < 4; ++r) {
                const int pos = (acc[ms][ns][r] >= 0.f);
                const size_t o = (size_t)(m + r) * HV_D + n;
                hv_out[o] = pos ? 1.f : -1.f;
                hvb[o] = (signed char)(pos ? 1 : -1);
            }
        }
    }
}

// ---------- G2: scores = hv_bin @ class_hv, exact in i8 (K=8192) ----------
// Same structure: 128x256 block, BK=64, double-buffered LDS (48 KB), 128 iters.
__launch_bounds__(256, 2)
__global__ void k_gemm2(const signed char* __restrict__ hvb, const signed char* __restrict__ cT,
                        float* __restrict__ scores) {
    __shared__ signed char sA[2][128 * 64];   // 8 KB per buf
    __shared__ signed char sB[2][256 * 64];   // 16 KB per buf
    const int t = threadIdx.x;
    const int w = t >> 6, l = t & 63;
    const int m0 = blockIdx.y * 128, n0 = blockIdx.x * 256;
    const int wm = (w >> 1) * 64, wn = (w & 1) * 128;
    const int lm = l & 15, kq = l >> 4;
    const int sr  = t >> 2;
    const int sch = (t & 3) ^ ((sr ^ (sr >> 2)) & 3);
    const int csw = ((kq ^ ((lm ^ (lm >> 2)) & 3)) & 3) * 16;   // bytes

    intx4 acc[4][8] = {};

    auto stage = [&](int k0, int p) {
#pragma unroll
        for (int i = 0; i < 2; ++i)
            GLD16(hvb + (size_t)(m0 + i * 64 + sr) * HV_D + k0 + sch * 16,
                  (char*)&sA[p][i * 4096] + t * 16);
#pragma unroll
        for (int i = 0; i < 4; ++i)
            GLD16(cT + (size_t)(n0 + i * 64 + sr) * HV_D + k0 + sch * 16,
                  (char*)&sB[p][i * 4096] + t * 16);
    };

    stage(0, 0);
    const int NIT = HV_D / 64;   // 128
    for (int it = 0; it < NIT; ++it) {
        const int p = it & 1;
        __syncthreads();
        if (it + 1 < NIT) stage((it + 1) * 64, p ^ 1);
        intx4 b[8];
#pragma unroll
        for (int ns = 0; ns < 8; ++ns)
            b[ns] = *(const intx4*)&sB[p][(wn + ns * 16 + lm) * 64 + csw];
#pragma unroll
        for (int ms = 0; ms < 4; ++ms) {
            intx4 a = *(const intx4*)&sA[p][(wm + ms * 16 + lm) * 64 + csw];
#pragma unroll
            for (int ns = 0; ns < 8; ++ns)
                acc[ms][ns] = __builtin_amdgcn_mfma_i32_16x16x64_i8(a, b[ns], acc[ms][ns], 0, 0, 0);
        }
    }

#pragma unroll
    for (int ms = 0; ms < 4; ++ms) {
#pragma unroll
        for (int ns = 0; ns < 8; ++ns) {
            const int m = m0 + wm + ms * 16 + kq * 4;
            const int n = n0 + wn + ns * 16 + lm;
            if (n < NC) {
#pragma unroll
                for (int r = 0; r < 4; ++r)
                    scores[(size_t)(m + r) * NC + n] = (float)acc[ms][ns][r];
            }
        }
    }
}

extern "C" void kernel_launch(void* const* d_in, const int* in_sizes, int n_in,
                              void* d_out, int out_size, void* d_ws, size_t ws_size,
                              hipStream_t stream) {
    const float* x    = (const float*)d_in[0];   // [16384][2048]
    const float* proj = (const float*)d_in[1];   // [2048][8192]
    const float* chv  = (const float*)d_in[2];   // [8192][1000]
    float* out    = (float*)d_out;
    float* scores = out;                          // [16384][1000]
    float* hv_out = out + (size_t)SCORES_N;       // [16384][8192]

    // workspace layout (total 310,378,496 B)
    char* ws = (char*)d_ws;
    _Float16*    xh  = (_Float16*)(ws);                         //  64 MiB
    _Float16*    xl  = (_Float16*)(ws + (size_t)67108864);      //  64 MiB
    _Float16*    pT  = (_Float16*)(ws + (size_t)134217728);     //  32 MiB
    signed char* cT  = (signed char*)(ws + (size_t)167772160);  //   8 MiB
    signed char* hvb = (signed char*)(ws + (size_t)176160768);  // 128 MiB

    k_split<<<(B_DIM * IN_D / 4) / 256, 256, 0, stream>>>(x, xh, xl);
    k_transpose_proj<<<dim3(HV_D / 64, IN_D / 64), 256, 0, stream>>>(proj, pT);
    k_pack_class<<<dim3(NCP / 64, HV_D / 64), 256, 0, stream>>>(chv, cT);
    k_gemm1<<<dim3(HV_D / 256, B_DIM / 128), 256, 0, stream>>>(xh, xl, pT, hv_out, hvb);
    k_gemm2<<<dim3(NCP / 256, B_DIM / 128), 256, 0, stream>>>(hvb, cT, scores);
}

// Round 5
// 1620.420 us; speedup vs baseline: 1.1069x; 1.1069x over previous
//
#include <hip/hip_runtime.h>
#include <hip/hip_bf16.h>

typedef _Float16 half8  __attribute__((ext_vector_type(8)));
typedef _Float16 half4_t __attribute__((ext_vector_type(4)));
typedef float    floatx4 __attribute__((ext_vector_type(4)));
typedef int      intx4   __attribute__((ext_vector_type(4)));

#define B_DIM   16384
#define IN_D    2048
#define HV_D    8192
#define NC      1000
#define NCP     1024
#define SCORES_N (B_DIM * NC)

// async global->LDS, 16B per lane; LDS side is wave-uniform base + lane*16
#define GLD16(gp, lp) __builtin_amdgcn_global_load_lds( \
    (const __attribute__((address_space(1))) void*)(gp), \
    (__attribute__((address_space(3))) void*)(lp), 16, 0, 0)

// ---------- P1: Dekker split x (fp32) -> x_hi + x_lo (fp16), exact vs fp32 ----------
__global__ void k_split(const float* __restrict__ x, _Float16* __restrict__ xh,
                        _Float16* __restrict__ xl) {
    size_t i = (size_t)blockIdx.x * 256 + threadIdx.x;
    floatx4 v = ((const floatx4*)x)[i];
    half4_t h, l;
#pragma unroll
    for (int j = 0; j < 4; ++j) {
        _Float16 hh = (_Float16)v[j];
        h[j] = hh;
        l[j] = (_Float16)(v[j] - (float)hh);
    }
    ((half4_t*)xh)[i] = h;
    ((half4_t*)xl)[i] = l;
}

// ---------- P2: proj [K=2048][N=8192] fp32 -> projT [N][K] fp16 (LDS-tiled) ----------
__global__ void k_transpose_proj(const float* __restrict__ p, _Float16* __restrict__ pT) {
    __shared__ float tile[64][65];
    const int t = threadIdx.x;
    const int nt = blockIdx.x * 64;
    const int kt = blockIdx.y * 64;
    const int tr = t >> 4, tc = (t & 15) * 4;
#pragma unroll
    for (int s = 0; s < 4; ++s) {
        int r = tr + s * 16;
        floatx4 v = *(const floatx4*)&p[(size_t)(kt + r) * HV_D + nt + tc];
        tile[r][tc] = v[0]; tile[r][tc + 1] = v[1];
        tile[r][tc + 2] = v[2]; tile[r][tc + 3] = v[3];
    }
    __syncthreads();
#pragma unroll
    for (int s = 0; s < 4; ++s) {
        int rn = tr + s * 16;
        half4_t o;
#pragma unroll
        for (int j = 0; j < 4; ++j) o[j] = (_Float16)tile[tc + j][rn];
        *(half4_t*)&pT[(size_t)(nt + rn) * IN_D + kt + tc] = o;
    }
}

// ---------- P3: class_hv [8192][1000] fp32 -> classT [1024][8192] i8 (coalesced, LDS transpose) ----------
__global__ void k_pack_class(const float* __restrict__ c, signed char* __restrict__ cT) {
    __shared__ signed char tile[64][68];
    const int t = threadIdx.x;
    const int nt = blockIdx.x * 64;
    const int kt = blockIdx.y * 64;
    const int nl = t & 63;
    const int n = nt + nl;
#pragma unroll
    for (int s = 0; s < 16; ++s) {
        const int kl = s * 4 + (t >> 6);
        signed char v = 0;
        if (n < NC) {
            float f = c[(size_t)(kt + kl) * NC + n];
            v = (f >= 0.f) ? (signed char)1 : (signed char)-1;
        }
        tile[kl][nl] = v;
    }
    __syncthreads();
    const int wn = t >> 2;
    const int wk = (t & 3) * 16;
    intx4 o;
    signed char* ob = (signed char*)&o;
#pragma unroll
    for (int j = 0; j < 16; ++j) ob[j] = tile[wk + j][wn];
    *(intx4*)&cT[(size_t)(nt + wn) * HV_D + kt + wk] = o;
}

// ---------- G1: hv = x@proj via fp16 hi/lo split, binarize, write fp32 + i8 ----------
// R3 structure verbatim (proven: 0 LDS conflicts, 874 us whole). 128(M)x256(N), BK=64,
// 4 waves 2x2, wave tile 64x128. LDS rows 128 B, slot = chunk ^ (row&7).
// Split into two half-M dispatches (mbase param) so sub-500us pipeline stages become
// visible in rocprof top-5 (diagnostic for the unexplained ~760us rest).
__launch_bounds__(256, 2)
__global__ void k_gemm1(const _Float16* __restrict__ xh, const _Float16* __restrict__ xl,
                        const _Float16* __restrict__ pT,
                        float* __restrict__ hv_out, signed char* __restrict__ hvb,
                        int mbase) {
    __shared__ _Float16 sAh[128 * 64];   // 16 KB
    __shared__ _Float16 sAl[128 * 64];   // 16 KB
    __shared__ _Float16 sB [256 * 64];   // 32 KB
    const int t = threadIdx.x;
    const int w = t >> 6, l = t & 63;
    const int m0 = mbase + blockIdx.y * 128, n0 = blockIdx.x * 256;
    const int wm = (w >> 1) * 64, wn = (w & 1) * 128;
    const int lm = l & 15, kq = l >> 4;
    const int srow  = w * 8 + (l >> 3);                  // + i*32
    const int scol  = (((l & 7) ^ ((l >> 3) & 7))) * 8;  // swizzled source chunk (f16 units)
    const int sbyte = w * 1024 + l * 16;                 // + i*4096

    floatx4 acc[4][8] = {};

    for (int k0 = 0; k0 < IN_D; k0 += 64) {
        __syncthreads();
#pragma unroll
        for (int i = 0; i < 4; ++i) {
            const size_t ga = (size_t)(m0 + srow + i * 32) * IN_D + k0 + scol;
            const int lo = sbyte + i * 4096;
            GLD16(xh + ga, (char*)sAh + lo);
            GLD16(xl + ga, (char*)sAl + lo);
        }
#pragma unroll
        for (int i = 0; i < 8; ++i) {
            const size_t gb = (size_t)(n0 + srow + i * 32) * IN_D + k0 + scol;
            GLD16(pT + gb, (char*)sB + sbyte + i * 4096);
        }
        __syncthreads();
#pragma unroll
        for (int ks = 0; ks < 2; ++ks) {
            const int csw = ((ks * 4 + kq) ^ (lm & 7)) * 8;   // swizzled slot (f16 units)
            half8 b[8];
#pragma unroll
            for (int ns = 0; ns < 8; ++ns)
                b[ns] = *(const half8*)&sB[(wn + ns * 16 + lm) * 64 + csw];
#pragma unroll
            for (int ms = 0; ms < 4; ++ms) {
                half8 a = *(const half8*)&sAh[(wm + ms * 16 + lm) * 64 + csw];
#pragma unroll
                for (int ns = 0; ns < 8; ++ns)
                    acc[ms][ns] = __builtin_amdgcn_mfma_f32_16x16x32_f16(a, b[ns], acc[ms][ns], 0, 0, 0);
            }
#pragma unroll
            for (int ms = 0; ms < 4; ++ms) {
                half8 a = *(const half8*)&sAl[(wm + ms * 16 + lm) * 64 + csw];
#pragma unroll
                for (int ns = 0; ns < 8; ++ns)
                    acc[ms][ns] = __builtin_amdgcn_mfma_f32_16x16x32_f16(a, b[ns], acc[ms][ns], 0, 0, 0);
            }
        }
    }

    // epilogue: C/D layout col=lane&15, row=(lane>>4)*4+reg
#pragma unroll
    for (int ms = 0; ms < 4; ++ms) {
#pragma unroll
        for (int ns = 0; ns < 8; ++ns) {
            const int m = m0 + wm + ms * 16 + kq * 4;
            const int n = n0 + wn + ns * 16 + lm;
#pragma unroll
            for (int r = 0; r < 4; ++r) {
                const int pos = (acc[ms][ns][r] >= 0.f);
                const size_t o = (size_t)(m + r) * HV_D + n;
                hv_out[o] = pos ? 1.f : -1.f;
                hvb[o] = (signed char)(pos ? 1 : -1);
            }
        }
    }
}

// ---------- G2: scores = hv_bin @ class_hv, exact in i8 (K=8192) ----------
// R3 structure verbatim: 128x256 block, BK=128 (128-B rows, proven-zero-conflict swizzle
// family), wave tile 64x128, 64 k-iters. Kept IDENTICAL so its counters, once visible,
// describe a known kernel.
__launch_bounds__(256, 2)
__global__ void k_gemm2(const signed char* __restrict__ hvb, const signed char* __restrict__ cT,
                        float* __restrict__ scores) {
    __shared__ signed char sA[128 * 128];   // 16 KB
    __shared__ signed char sB[256 * 128];   // 32 KB
    const int t = threadIdx.x;
    const int w = t >> 6, l = t & 63;
    const int m0 = blockIdx.y * 128, n0 = blockIdx.x * 256;
    const int wm = (w >> 1) * 64, wn = (w & 1) * 128;
    const int lm = l & 15, kq = l >> 4;
    const int srow  = w * 8 + (l >> 3);                   // + i*32
    const int scol  = (((l & 7) ^ ((l >> 3) & 7))) * 16;  // swizzled source chunk (bytes)
    const int sbyte = w * 1024 + l * 16;                  // + i*4096

    intx4 acc[4][8] = {};

    for (int k0 = 0; k0 < HV_D; k0 += 128) {
        __syncthreads();
#pragma unroll
        for (int i = 0; i < 4; ++i)
            GLD16(hvb + (size_t)(m0 + srow + i * 32) * HV_D + k0 + scol,
                  (char*)sA + sbyte + i * 4096);
#pragma unroll
        for (int i = 0; i < 8; ++i)
            GLD16(cT + (size_t)(n0 + srow + i * 32) * HV_D + k0 + scol,
                  (char*)sB + sbyte + i * 4096);
        __syncthreads();
#pragma unroll
        for (int ks = 0; ks < 2; ++ks) {
            const int csw = ((ks * 4 + kq) ^ (lm & 7)) * 16;  // bytes
            intx4 b[8];
#pragma unroll
            for (int ns = 0; ns < 8; ++ns)
                b[ns] = *(const intx4*)&sB[(wn + ns * 16 + lm) * 128 + csw];
#pragma unroll
            for (int ms = 0; ms < 4; ++ms) {
                intx4 a = *(const intx4*)&sA[(wm + ms * 16 + lm) * 128 + csw];
#pragma unroll
                for (int ns = 0; ns < 8; ++ns)
                    acc[ms][ns] = __builtin_amdgcn_mfma_i32_16x16x64_i8(a, b[ns], acc[ms][ns], 0, 0, 0);
            }
        }
    }

#pragma unroll
    for (int ms = 0; ms < 4; ++ms) {
#pragma unroll
        for (int ns = 0; ns < 8; ++ns) {
            const int m = m0 + wm + ms * 16 + kq * 4;
            const int n = n0 + wn + ns * 16 + lm;
            if (n < NC) {
#pragma unroll
                for (int r = 0; r < 4; ++r)
                    scores[(size_t)(m + r) * NC + n] = (float)acc[ms][ns][r];
            }
        }
    }
}

extern "C" void kernel_launch(void* const* d_in, const int* in_sizes, int n_in,
                              void* d_out, int out_size, void* d_ws, size_t ws_size,
                              hipStream_t stream) {
    const float* x    = (const float*)d_in[0];   // [16384][2048]
    const float* proj = (const float*)d_in[1];   // [2048][8192]
    const float* chv  = (const float*)d_in[2];   // [8192][1000]
    float* out    = (float*)d_out;
    float* scores = out;                          // [16384][1000]
    float* hv_out = out + (size_t)SCORES_N;       // [16384][8192]

    // workspace layout (total 310,378,496 B)
    char* ws = (char*)d_ws;
    _Float16*    xh  = (_Float16*)(ws);                         //  64 MiB
    _Float16*    xl  = (_Float16*)(ws + (size_t)67108864);      //  64 MiB
    _Float16*    pT  = (_Float16*)(ws + (size_t)134217728);     //  32 MiB
    signed char* cT  = (signed char*)(ws + (size_t)167772160);  //   8 MiB
    signed char* hvb = (signed char*)(ws + (size_t)176160768);  // 128 MiB

    k_split<<<(B_DIM * IN_D / 4) / 256, 256, 0, stream>>>(x, xh, xl);
    k_transpose_proj<<<dim3(HV_D / 64, IN_D / 64), 256, 0, stream>>>(proj, pT);
    k_pack_class<<<dim3(NCP / 64, HV_D / 64), 256, 0, stream>>>(chv, cT);
    // gemm1 split into two half-M dispatches (diagnostic: lowers top-5 visibility
    // threshold from ~874us to ~440us so the unexplained pipeline cost surfaces)
    k_gemm1<<<dim3(HV_D / 256, B_DIM / 256), 256, 0, stream>>>(xh, xl, pT, hv_out, hvb, 0);
    k_gemm1<<<dim3(HV_D / 256, B_DIM / 256), 256, 0, stream>>>(xh, xl, pT, hv_out, hvb, B_DIM / 2);
    k_gemm2<<<dim3(NCP / 256, B_DIM / 128), 256, 0, stream>>>(hvb, cT, scores);
}